// Round 1
// baseline (5522.230 us; speedup 1.0000x reference)
//
#include <hip/hip_runtime.h>
#include <math.h>
#include <stdint.h>

// Greedy DPP MAP (Chen et al. 2018) — persistent-kernel implementation.
// N=8192 items, D=512 features, K=256 selections.
// One thread owns one row n: its d[n] (register), its FN row, its cis column.
// Per step: global argmax via per-block partials + redundant final reduce
// (ONE grid barrier per step, ping-pong partials buffer).
//
// ws layout: [0,8) barrier {cnt,gen} (memset to 0 each launch)
//            [256, 256+2*NBLK*8) Pick partials[2][NBLK]
//            [4096, +16MB) FN  = normalized features (f32, row-major)
//            [+16MB, +24MB) cis = e-rows, K x N f32  (row t written at step t)
// total needed ~25.2 MB.

#define N 8192
#define D 512
#define K 256
#define LAMBDA_REG 0.01f
#define NBLK 64
#define NTHR 128   // NBLK*NTHR == N

#define SCOPE __HIP_MEMORY_SCOPE_AGENT

struct __align__(8) Pick { float v; int i; };

__device__ __forceinline__ bool better(float av, int ai, float bv, int bi) {
    // first-max semantics (matches jnp.argmax tie-break: lowest index wins)
    return (av > bv) || (av == bv && ai < bi);
}

__device__ __forceinline__ void grid_barrier(unsigned* bar) {
    __threadfence();          // release this thread's writes (all threads)
    __syncthreads();
    if (threadIdx.x == 0) {
        unsigned* cnt = bar;
        unsigned* gen = bar + 1;
        unsigned g = __hip_atomic_load(gen, __ATOMIC_RELAXED, SCOPE);
        unsigned a = __hip_atomic_fetch_add(cnt, 1u, __ATOMIC_ACQ_REL, SCOPE);
        if (a == NBLK - 1) {
            __hip_atomic_store(cnt, 0u, __ATOMIC_RELAXED, SCOPE);
            __hip_atomic_fetch_add(gen, 1u, __ATOMIC_ACQ_REL, SCOPE);
        } else {
            while (__hip_atomic_load(gen, __ATOMIC_RELAXED, SCOPE) == g)
                __builtin_amdgcn_s_sleep(1);
        }
    }
    __syncthreads();
    __threadfence();          // acquire: invalidate stale caches before reads
}

__device__ __forceinline__ Pick block_argmax(float v, int idx, Pick* lds_wave) {
    const int tid = threadIdx.x;
    #pragma unroll
    for (int m = 32; m > 0; m >>= 1) {
        float ov = __shfl_xor(v, m, 64);
        int   oi = __shfl_xor(idx, m, 64);
        if (better(ov, oi, v, idx)) { v = ov; idx = oi; }
    }
    if ((tid & 63) == 0) { lds_wave[tid >> 6].v = v; lds_wave[tid >> 6].i = idx; }
    __syncthreads();
    Pick p = lds_wave[0];
    #pragma unroll
    for (int w = 1; w < NTHR / 64; ++w) {
        Pick o = lds_wave[w];
        if (better(o.v, o.i, p.v, p.i)) p = o;
    }
    return p;
}

__global__ __launch_bounds__(NTHR, 1) void dpp_kernel(
        const float* __restrict__ F, const float* __restrict__ q,
        float* __restrict__ FN, float* __restrict__ cis,
        Pick* __restrict__ parts, unsigned* __restrict__ bar,
        int* __restrict__ out)
{
    const int tid = threadIdx.x;
    const int blk = blockIdx.x;
    const int n = blk * NTHR + tid;   // this thread's row

    __shared__ float lds_gj[D];       // fn_j staged per step
    __shared__ float lds_cj[K];       // cis[0..t-1][j] staged per step
    __shared__ Pick  lds_wave[NTHR / 64];
    __shared__ Pick  lds_final;

    // ---- init: normalize row n, init d ----
    const float4* f4  = reinterpret_cast<const float4*>(F) + (size_t)n * (D / 4);
    float4*       fn4 = reinterpret_cast<float4*>(FN) + (size_t)n * (D / 4);
    float ss = 0.f;
    #pragma unroll 8
    for (int i = 0; i < D / 4; ++i) {
        float4 v = f4[i];
        ss = fmaf(v.x, v.x, ss); ss = fmaf(v.y, v.y, ss);
        ss = fmaf(v.z, v.z, ss); ss = fmaf(v.w, v.w, ss);
    }
    const float norm = sqrtf(ss);
    float ssn = 0.f;
    #pragma unroll 4
    for (int i = 0; i < D / 4; ++i) {
        float4 v = f4[i];
        float4 w;
        w.x = v.x / norm; w.y = v.y / norm; w.z = v.z / norm; w.w = v.w / norm;
        fn4[i] = w;
        ssn = fmaf(w.x, w.x, ssn); ssn = fmaf(w.y, w.y, ssn);
        ssn = fmaf(w.z, w.z, ssn); ssn = fmaf(w.w, w.w, ssn);
    }
    const float qn = q[n];
    // d0 = sqrt(q*q)*S_ii + lambda, mirroring reference rounding
    float dloc = fmaf(sqrtf(qn * qn), ssn, LAMBDA_REG);
    bool masked = false;

    {
        Pick p = block_argmax(masked ? -INFINITY : dloc, n, lds_wave);
        if (tid == 0) parts[blk] = p;            // buffer 0
    }
    grid_barrier(bar);

    const float4* FN4 = reinterpret_cast<const float4*>(FN);

    for (int t = 0; t < K; ++t) {
        // ---- final argmax (redundant in every block, deterministic) ----
        {
            const Pick* pbuf = parts + (t & 1) * NBLK;
            if (tid < 64) {
                float v = -INFINITY; int idx = 0x7fffffff;
                if (tid < NBLK) { Pick p = pbuf[tid]; v = p.v; idx = p.i; }
                #pragma unroll
                for (int m = 32; m > 0; m >>= 1) {
                    float ov = __shfl_xor(v, m, 64);
                    int   oi = __shfl_xor(idx, m, 64);
                    if (better(ov, oi, v, idx)) { v = ov; idx = oi; }
                }
                if (tid == 0) { lds_final.v = v; lds_final.i = idx; }
            }
            __syncthreads();
        }
        const float dj = lds_final.v;
        const int   j  = lds_final.i;

        if (blk == 0 && tid == 0) out[t] = j;
        if (t == K - 1) break;

        const float sj = sqrtf(dj);
        const float qj = q[j];

        // ---- stage fn_j (2KB) and cis[0..t-1][j] into LDS ----
        reinterpret_cast<float4*>(lds_gj)[tid] = FN4[(size_t)j * (D / 4) + tid]; // NTHR==D/4
        for (int tt = tid; tt < t; tt += NTHR)
            lds_cj[tt] = cis[(size_t)tt * N + j];
        __syncthreads();

        // ---- L[j,n] = sqrt(qj*qn) * <fn_j, fn_n> (+lambda at n==j) ----
        float4 a = {0.f, 0.f, 0.f, 0.f};
        const float4* row = FN4 + (size_t)n * (D / 4);
        const float4* g4  = reinterpret_cast<const float4*>(lds_gj);
        #pragma unroll 8
        for (int i = 0; i < D / 4; ++i) {
            float4 v = row[i], g = g4[i];
            a.x = fmaf(v.x, g.x, a.x); a.y = fmaf(v.y, g.y, a.y);
            a.z = fmaf(v.z, g.z, a.z); a.w = fmaf(v.w, g.w, a.w);
        }
        float Ljn = sqrtf(qj * qn) * ((a.x + a.y) + (a.z + a.w));
        if (n == j) Ljn += LAMBDA_REG;

        // ---- cdot = sum_t cis[t][j] * cis[t][n] ----
        float cd = 0.f;
        #pragma unroll 4
        for (int tt = 0; tt < t; ++tt)
            cd = fmaf(lds_cj[tt], cis[(size_t)tt * N + n], cd);

        const float e = (Ljn - cd) / sj;
        cis[(size_t)t * N + n] = e;
        dloc = fmaf(-e, e, dloc);
        if (n == j) masked = true;

        __syncthreads();   // lds_wave / lds_cj WAR protection
        Pick p = block_argmax(masked ? -INFINITY : dloc, n, lds_wave);
        if (tid == 0) parts[((t + 1) & 1) * NBLK + blk] = p;
        grid_barrier(bar);
    }
}

extern "C" void kernel_launch(void* const* d_in, const int* in_sizes, int n_in,
                              void* d_out, int out_size, void* d_ws, size_t ws_size,
                              hipStream_t stream) {
    const float* F = (const float*)d_in[0];
    const float* q = (const float*)d_in[1];
    int* out = (int*)d_out;

    uint8_t* w = (uint8_t*)d_ws;
    unsigned* bar  = (unsigned*)w;
    Pick*    parts = (Pick*)(w + 256);
    float*   FN    = (float*)(w + 4096);
    float*   cis   = (float*)(w + 4096 + (size_t)N * D * sizeof(float));
    // total ws needed: 4096 + 16MB (FN) + 8MB (cis) ~= 25.2 MB

    hipMemsetAsync(d_ws, 0, 256, stream);   // zero barrier state each launch
    hipLaunchKernelGGL(dpp_kernel, dim3(NBLK), dim3(NTHR), 0, stream,
                       F, q, FN, cis, parts, bar, out);
}